// Round 7
// baseline (297.539 us; speedup 1.0000x reference)
//
#include <hip/hip_runtime.h>
#include <math.h>

// GGNN message-passing GRU, N=2048, SD=32, MD=16, 10 steps — single persistent
// kernel. Round-6 math (proven absmax 0.0) at 4 waves/SIMD: 256 blocks x 1024
// threads = one 16-wave block per CU. Block owns nodes [8b,8b+8); its J-slice
// (64 KB) lives XOR-swizzled in LDS for all 10 steps; h/msg/aj in LDS; only ai
// (transposed [m][i], double-buffered ws) crosses blocks per step.
// TOOLCHAIN LAW (rounds 4/5/6): launch_bounds 2nd arg w => VGPR cap 256/w.
//   w=4 -> 64-reg clamp + scratch spill (WRITE_SIZE exploded). w=2 -> 128 cap,
//   clean. 16 waves/CU needs <=128 VGPR, so (1024,2) is the only safe choice.

#define GN 2048
#define GSD 32
#define GMD 16
#define GSTEPS 10
#define NPB 8            // nodes per block
#define NBLK (GN / NPB)  // 256 blocks
#define BLK 1024

__device__ __forceinline__ void grid_barrier(int* __restrict__ bar, int epoch)
{
    __syncthreads();
    if (threadIdx.x == 0) {
        __threadfence();   // release: writeback dirty L2 (device scope)
        const int leaf = blockIdx.x & 7;
        const int old = __hip_atomic_fetch_add(&bar[leaf * 16], 1,
                             __ATOMIC_RELAXED, __HIP_MEMORY_SCOPE_AGENT);
        if (old == epoch * (NBLK / 8) - 1)   // last arriver on this leaf
            __hip_atomic_fetch_add(&bar[128], 1,
                                   __ATOMIC_RELAXED, __HIP_MEMORY_SCOPE_AGENT);
        while (__hip_atomic_load(&bar[128], __ATOMIC_RELAXED,
                                 __HIP_MEMORY_SCOPE_AGENT) < epoch * 8)
            __builtin_amdgcn_s_sleep(2);
        __threadfence();   // acquire: invalidate stale L1/L2
    }
    __syncthreads();
}

__global__ __launch_bounds__(BLK, 2)
void ggnn_persistent(const float* __restrict__ J,
                     const float* __restrict__ b,
                     const float* __restrict__ Wmsg,
                     const float* __restrict__ bmsg,
                     const float* __restrict__ Wih,
                     const float* __restrict__ bih,
                     const float* __restrict__ bhh,
                     const float* __restrict__ Wro,
                     const float* __restrict__ bro,
                     float* __restrict__ Jt,
                     float* __restrict__ aiT0,
                     float* __restrict__ aiT1,
                     float* __restrict__ logits,
                     int* __restrict__ bar,
                     float* __restrict__ out)
{
    __shared__ __align__(16) float sJ[NPB][GN];    // 64 KB, XOR-swizzled rows
    __shared__ float sWih[96][49];
    __shared__ float sWhi[GMD][GSD + 1];
    __shared__ float sWhj[GMD][GSD + 1];
    __shared__ float sh[NPB][GSD];
    __shared__ float sx[NPB][GSD + GMD];
    __shared__ float sg[NPB][3 * GSD];
    __shared__ float smsg[NPB][GMD];
    __shared__ __align__(16) float saj[NPB][GMD];
    __shared__ __align__(16) float spart[16][2][4][4][4]; // [wave][jh][mq][jl][mi]
    __shared__ float swJ[GMD], swbi[GMD], swbj[GMD], sbm[GMD];
    __shared__ float sbih[3 * GSD], sbhh[3 * GSD];
    __shared__ float sb[NPB], swro[GSD];
    __shared__ float sredm[8], sreds[8];

    // transpose staging tile reuses sJ's storage (sJ filled only after the
    // grid barrier that follows the transpose — no overlap).
    float (*ttile)[65] = reinterpret_cast<float(*)[65]>(&sJ[0][0]);

    const int t = threadIdx.x;
    const int jb = blockIdx.x * NPB;

    // ---- stage weights; zero block-local state ----
    for (int idx = t; idx < 96 * 48; idx += BLK) sWih[idx / 48][idx % 48] = Wih[idx];
    if (t < GMD * GSD) {
        const int m = t >> 5, k = t & 31;
        sWhi[m][k] = Wmsg[m * 67 + k];
        sWhj[m][k] = Wmsg[m * 67 + GSD + k];
    }
    if (t < GMD) { swJ[t] = Wmsg[t * 67 + 64]; swbi[t] = Wmsg[t * 67 + 65];
                   swbj[t] = Wmsg[t * 67 + 66]; sbm[t] = bmsg[t]; }
    if (t < 96) { sbih[t] = bih[t]; sbhh[t] = bhh[t]; }
    if (t < GSD) swro[t] = Wro[t];
    if (t < NPB) sb[t] = b[jb + t];
    if (t < NPB * GSD) { sh[t >> 5][t & 31] = 0.f; sx[t >> 5][t & 31] = 0.f; }
    if (t < NPB * GMD) smsg[t >> 4][t & 15] = 0.f;
    __syncthreads();

    // ---- init aj (LDS) + aiT0 (global) for step 0 ----
    if (t < NPB * GMD) {
        const int n = t >> 4, m = t & 15;
        saj[n][m] = sb[n] * swbj[m];
        aiT0[(size_t)m * GN + jb + n] = fmaf(sb[n], swbi[m], sbm[m]);
    }

    // ---- transpose: 4 64x64 tiles per block ----
#pragma unroll
    for (int tt = 0; tt < 4; ++tt) {
        const int tile = blockIdx.x * 4 + tt;
        const int bx = tile & 31, by = tile >> 5;
        __syncthreads();
        for (int r = t >> 6; r < 64; r += 16)
            ttile[r][t & 63] = J[(size_t)(by * 64 + r) * GN + bx * 64 + (t & 63)];
        __syncthreads();
        for (int r = t >> 6; r < 64; r += 16)
            Jt[(size_t)(bx * 64 + r) * GN + by * 64 + (t & 63)] = ttile[t & 63][r];
    }

    int epoch = 1;
    grid_barrier(bar, epoch); ++epoch;

    // ---- load this block's 8 Jt rows into LDS once, XOR-swizzled ----
    // 16B-granule qi stored at byte (qi*16) ^ (((qi>>3)&7)<<4); bijective.
    for (int idx = t; idx < NPB * (GN / 4); idx += BLK) {   // 4096 float4s
        const int row = idx >> 9;
        const int qi  = idx & 511;
        const float4 v = *(const float4*)&Jt[(size_t)(jb + row) * GN + qi * 4];
        const int byte = (qi * 16) ^ (((qi >> 3) & 7) << 4);
        *(float4*)((char*)&sJ[row][0] + byte) = v;
    }
    __syncthreads();

    // ---- stream decomposition: t = isub*8 + jh*4 + mq ----
    const int mq   = t & 3;          // m-quad: m = mq*4 + mi
    const int jh   = (t >> 2) & 1;   // j-half (4 j's each)
    const int isub = t >> 3;         // 0..127, owns i in [isub*16, isub*16+16)
    const int i0 = isub * 16;
    // read-side swizzle: qi_lin = isub*4+c -> (qi_lin>>3)&7 == (isub>>1)&7
    const int swz = ((isub >> 1) & 7) << 4;
    const char* sJb = (const char*)&sJ[0][0];

    float wj[4];
#pragma unroll
    for (int mi = 0; mi < 4; ++mi) wj[mi] = swJ[mq * 4 + mi];

    const float* aiIn = aiT0;
    float* aiOut = aiT1;

    for (int s = 0; s < GSTEPS; ++s) {
        // ---- phase 2: relu-sum stream; J from LDS, ai from global (L2/L3) ----
        float ajv[4][4];
#pragma unroll
        for (int jl = 0; jl < 4; ++jl) {
            const float4 a = *(const float4*)&saj[jh * 4 + jl][mq * 4];
            ajv[jl][0] = a.x; ajv[jl][1] = a.y; ajv[jl][2] = a.z; ajv[jl][3] = a.w;
        }
        const float* __restrict__ Ar[4];
#pragma unroll
        for (int mi = 0; mi < 4; ++mi) Ar[mi] = aiIn + (size_t)(mq * 4 + mi) * GN + i0;

        float acc[4][4];
#pragma unroll
        for (int jl = 0; jl < 4; ++jl)
#pragma unroll
            for (int mi = 0; mi < 4; ++mi) acc[jl][mi] = 0.f;

#pragma unroll 2
        for (int c = 0; c < 4; ++c) {
            float jv[4][4], av[4][4];
            const int jbyte = (i0 * 4 + c * 16) ^ swz;
#pragma unroll
            for (int jl = 0; jl < 4; ++jl) {
                const float4 v = *(const float4*)(sJb + (jh * 4 + jl) * (GN * 4) + jbyte);
                jv[jl][0] = v.x; jv[jl][1] = v.y; jv[jl][2] = v.z; jv[jl][3] = v.w;
            }
#pragma unroll
            for (int mi = 0; mi < 4; ++mi) {
                const float4 v = *(const float4*)(Ar[mi] + c * 4);
                av[mi][0] = v.x; av[mi][1] = v.y; av[mi][2] = v.z; av[mi][3] = v.w;
            }
#pragma unroll
            for (int q = 0; q < 4; ++q)
#pragma unroll
                for (int jl = 0; jl < 4; ++jl)
#pragma unroll
                    for (int mi = 0; mi < 4; ++mi)
                        acc[jl][mi] += fmaxf(fmaf(jv[jl][q], wj[mi],
                                                  av[mi][q] + ajv[jl][mi]), 0.f);
        }

        // reduce over isub-within-wave (lane bits 3..5)
#pragma unroll
        for (int d = 8; d < 64; d <<= 1)
#pragma unroll
            for (int jl = 0; jl < 4; ++jl)
#pragma unroll
                for (int mi = 0; mi < 4; ++mi)
                    acc[jl][mi] += __shfl_xor(acc[jl][mi], d, 64);

        if ((t & 63) < 8) {   // lane = jh*4 + mq
            const int w = t >> 6;
#pragma unroll
            for (int jl = 0; jl < 4; ++jl)
                *(float4*)&spart[w][jh][mq][jl][0] =
                    make_float4(acc[jl][0], acc[jl][1], acc[jl][2], acc[jl][3]);
        }
        __syncthreads();

        // combine 16 wave-partials, update msg (deterministic order)
        if (t < NPB * GMD) {
            const int j = t >> 4, m = t & 15;
            const int jhh = j >> 2, jl = j & 3, mqq = m >> 2, mi = m & 3;
            float ssum = 0.f;
#pragma unroll
            for (int w = 0; w < 16; ++w) ssum += spart[w][jhh][mqq][jl][mi];
            const float mnew = smsg[j][m] + ssum;
            smsg[j][m] = mnew;
            sx[j][GSD + m] = mnew;
        }
        __syncthreads();

        // ---- phase 3: g = W_ih @ x + b_ih ----
        if (t < NPB * 96) {
            const int node = t / 96, r = t - node * 96;
            float a = sbih[r];
#pragma unroll
            for (int c = 0; c < GSD + GMD; ++c) a = fmaf(sWih[r][c], sx[node][c], a);
            sg[node][r] = a;
        }
        __syncthreads();

        // GRU gates -> h_new
        if (t < NPB * GSD) {
            const int node = t >> 5, k = t & 31;
            const float gr = sg[node][k]           + sbhh[k];
            const float gz = sg[node][GSD + k]     + sbhh[GSD + k];
            const float gn = sg[node][2 * GSD + k];
            const float r_ = 1.f / (1.f + expf(-gr));
            const float z_ = 1.f / (1.f + expf(-gz));
            const float n_ = tanhf(fmaf(r_, sbhh[2 * GSD + k], gn));
            const float hn = (1.f - z_) * n_;
            sh[node][k] = hn;
            sx[node][k] = hn;
        }
        __syncthreads();

        if (s < GSTEPS - 1) {
            // ---- phase 1': ai (global, transposed) / aj (LDS) for next step ----
            if (t < 2 * NPB * GMD) {   // 256 threads
                const int which = t >> 7;
                const int node  = (t >> 4) & 7;
                const int m     = t & 15;
                if (which == 0) {
                    float a = fmaf(sb[node], swbi[m], sbm[m]);
#pragma unroll
                    for (int k = 0; k < GSD; ++k) a = fmaf(sWhi[m][k], sh[node][k], a);
                    aiOut[(size_t)m * GN + jb + node] = a;
                } else {
                    float a = sb[node] * swbj[m];
#pragma unroll
                    for (int k = 0; k < GSD; ++k) a = fmaf(sWhj[m][k], sh[node][k], a);
                    saj[node][m] = a;
                }
            }
            grid_barrier(bar, epoch); ++epoch;
            const float* tin = aiIn; aiIn = aiOut; aiOut = (float*)tin;
        }
    }

    // ---- readout logits ----
    if (t < NPB) {
        float a = bro[0];
#pragma unroll
        for (int k = 0; k < GSD; ++k) a = fmaf(sh[t][k], swro[k], a);
        logits[jb + t] = a;
    }
    grid_barrier(bar, epoch); ++epoch;

    // ---- softmax: computed redundantly per block (identical fixed order) ----
    float4 l4 = make_float4(0.f, 0.f, 0.f, 0.f);
    if (t < 512) {
        l4 = *(const float4*)&logits[t * 4];
        float lm = fmaxf(fmaxf(l4.x, l4.y), fmaxf(l4.z, l4.w));
#pragma unroll
        for (int d = 1; d < 64; d <<= 1) lm = fmaxf(lm, __shfl_xor(lm, d, 64));
        if ((t & 63) == 0) sredm[t >> 6] = lm;
    }
    __syncthreads();
    float gmax = sredm[0];
#pragma unroll
    for (int w = 1; w < 8; ++w) gmax = fmaxf(gmax, sredm[w]);
    if (t < 512) {
        float es = expf(l4.x - gmax) + expf(l4.y - gmax) +
                   expf(l4.z - gmax) + expf(l4.w - gmax);
#pragma unroll
        for (int d = 1; d < 64; d <<= 1) es += __shfl_xor(es, d, 64);
        if ((t & 63) == 0) sreds[t >> 6] = es;
    }
    __syncthreads();
    float tot = 0.f;
#pragma unroll
    for (int w = 0; w < 8; ++w) tot += sreds[w];
    if (t < NPB) out[jb + t] = expf(logits[jb + t] - gmax) / tot;
}

extern "C" void kernel_launch(void* const* d_in, const int* in_sizes, int n_in,
                              void* d_out, int out_size, void* d_ws, size_t ws_size,
                              hipStream_t stream)
{
    const float* J    = (const float*)d_in[0];
    const float* b    = (const float*)d_in[1];
    const float* Wmsg = (const float*)d_in[2];
    const float* bmsg = (const float*)d_in[3];
    const float* Wih  = (const float*)d_in[4];
    // d_in[5] = W_hh: unused by the reference math (only b_hh enters the gates)
    const float* bih  = (const float*)d_in[6];
    const float* bhh  = (const float*)d_in[7];
    const float* Wro  = (const float*)d_in[8];
    const float* bro  = (const float*)d_in[9];
    float* out = (float*)d_out;

    // workspace layout (floats)
    float* ws     = (float*)d_ws;
    float* Jt     = ws;                             // N*N
    float* aiT0   = Jt   + (size_t)GN * GN;         // MD*N
    float* aiT1   = aiT0 + (size_t)GN * GMD;        // MD*N
    float* logits = aiT1 + (size_t)GN * GMD;        // N
    int*   bar    = (int*)(logits + GN);            // barrier counters (1 KB)

    hipMemsetAsync(bar, 0, 1024, stream);
    ggnn_persistent<<<NBLK, BLK, 0, stream>>>(J, b, Wmsg, bmsg, Wih, bih, bhh,
                                              Wro, bro, Jt, aiT0, aiT1, logits,
                                              bar, out);
}

// Round 8
// 163.461 us; speedup vs baseline: 1.8202x; 1.8202x over previous
//
#include <hip/hip_runtime.h>
#include <math.h>

// GGNN message-passing GRU, N=2048, SD=32, MD=16, 10 steps — single persistent
// kernel, FENCELESS step barriers. Round-6 math/body (proven absmax 0.0).
// Cross-block data per step is only aiT (128 KB):
//   - written via __hip_atomic_store(AGENT) = write-through to the device
//     coherent point (no dirty per-XCD L2 lines),
//   - one PRIVATE buffer per step (written-once, read-once per launch), so
//     readers' plain float4 loads cold-miss L2 and fill correctly from L3 —
//     no stale-line hazard, no per-load atomics,
//   - __syncthreads before the leaf atomic drains vmcnt (compiler emits
//     s_waitcnt vmcnt(0) before s_barrier), so stores are L3-visible before
//     the flag. The step barrier therefore needs NO __threadfence (rounds 3-7
//     paid ~15-20 us/step for L2 writeback+invalidate in the fence pair).
// Only the post-transpose barrier keeps fences (Jt written by other blocks
// with normal stores, once per launch).
// TOOLCHAIN LAW (r4/5/7): launch_bounds != (512-thread, 2) clamps VGPR to 64
// and spills. Keep BLK=512, (BLK,2), 256 blocks, NPB=8, J-slice in LDS.

#define GN 2048
#define GSD 32
#define GMD 16
#define GSTEPS 10
#define NPB 8            // nodes per block
#define NBLK (GN / NPB)  // 256 blocks
#define BLK 512
#define AISTRIDE (GN * GMD + 256)   // per-step aiT buffer stride (+1KB guard)

template <bool FENCE>
__device__ __forceinline__ void grid_barrier(int* __restrict__ bar, int epoch)
{
    __syncthreads();   // all waves: s_waitcnt vmcnt(0) before s_barrier
    if (threadIdx.x == 0) {
        if (FENCE) __threadfence();
        const int leaf = blockIdx.x & 7;
        const int old = __hip_atomic_fetch_add(&bar[leaf * 16], 1,
                             __ATOMIC_RELAXED, __HIP_MEMORY_SCOPE_AGENT);
        if (old == epoch * (NBLK / 8) - 1)   // last arriver on this leaf
            __hip_atomic_fetch_add(&bar[128], 1,
                                   __ATOMIC_RELAXED, __HIP_MEMORY_SCOPE_AGENT);
        while (__hip_atomic_load(&bar[128], __ATOMIC_RELAXED,
                                 __HIP_MEMORY_SCOPE_AGENT) < epoch * 8)
            __builtin_amdgcn_s_sleep(2);
        if (FENCE) __threadfence();
        asm volatile("" ::: "memory");   // no compiler hoist past the spin
    }
    __syncthreads();
}

__global__ __launch_bounds__(BLK, 2)
void ggnn_persistent(const float* __restrict__ J,
                     const float* __restrict__ b,
                     const float* __restrict__ Wmsg,
                     const float* __restrict__ bmsg,
                     const float* __restrict__ Wih,
                     const float* __restrict__ bih,
                     const float* __restrict__ bhh,
                     const float* __restrict__ Wro,
                     const float* __restrict__ bro,
                     float* __restrict__ Jt,
                     float* __restrict__ aiBase,
                     float* __restrict__ logits,
                     int* __restrict__ bar,
                     float* __restrict__ out)
{
    __shared__ __align__(16) float sJ[NPB][GN];    // 64 KB, XOR-swizzled rows
    __shared__ float sWih[96][49];
    __shared__ float sWhi[GMD][GSD + 1];
    __shared__ float sWhj[GMD][GSD + 1];
    __shared__ float ttile[64][65];
    __shared__ float sh[NPB][GSD];
    __shared__ float sx[NPB][GSD + GMD];
    __shared__ float sg[NPB][3 * GSD];
    __shared__ float smsg[NPB][GMD];
    __shared__ __align__(16) float saj[NPB][GMD];
    __shared__ __align__(16) float spart[8][2][4][4][4]; // [wave][jh][mq][jl][mi]
    __shared__ float swJ[GMD], swbi[GMD], swbj[GMD], sbm[GMD];
    __shared__ float sbih[3 * GSD], sbhh[3 * GSD];
    __shared__ float sb[NPB], swro[GSD];
    __shared__ float sredm[8], sreds[8];

    const int t = threadIdx.x;
    const int jb = blockIdx.x * NPB;

    // ---- stage weights; zero block-local state ----
    for (int idx = t; idx < 96 * 48; idx += BLK) sWih[idx / 48][idx % 48] = Wih[idx];
    for (int idx = t; idx < GMD * GSD; idx += BLK) {
        const int m = idx >> 5, k = idx & 31;
        sWhi[m][k] = Wmsg[m * 67 + k];
        sWhj[m][k] = Wmsg[m * 67 + GSD + k];
    }
    if (t < GMD) { swJ[t] = Wmsg[t * 67 + 64]; swbi[t] = Wmsg[t * 67 + 65];
                   swbj[t] = Wmsg[t * 67 + 66]; sbm[t] = bmsg[t]; }
    if (t < 96) { sbih[t] = bih[t]; sbhh[t] = bhh[t]; }
    if (t < GSD) swro[t] = Wro[t];
    if (t < NPB) sb[t] = b[jb + t];
    if (t < NPB * GSD) { sh[t >> 5][t & 31] = 0.f; sx[t >> 5][t & 31] = 0.f; }
    if (t < NPB * GMD) smsg[t >> 4][t & 15] = 0.f;
    __syncthreads();

    // ---- init aj (LDS) + aiT buffer 0 (write-through) for step 0 ----
    if (t < NPB * GMD) {
        const int n = t >> 4, m = t & 15;
        saj[n][m] = sb[n] * swbj[m];
        __hip_atomic_store(&aiBase[(size_t)m * GN + jb + n],
                           fmaf(sb[n], swbi[m], sbm[m]),
                           __ATOMIC_RELAXED, __HIP_MEMORY_SCOPE_AGENT);
    }

    // ---- transpose: 4 64x64 tiles per block (normal stores -> fenced bar) ----
#pragma unroll
    for (int tt = 0; tt < 4; ++tt) {
        const int tile = blockIdx.x * 4 + tt;
        const int bx = tile & 31, by = tile >> 5;
        __syncthreads();
        for (int r = t >> 6; r < 64; r += 8)
            ttile[r][t & 63] = J[(size_t)(by * 64 + r) * GN + bx * 64 + (t & 63)];
        __syncthreads();
        for (int r = t >> 6; r < 64; r += 8)
            Jt[(size_t)(bx * 64 + r) * GN + by * 64 + (t & 63)] = ttile[t & 63][r];
    }

    int epoch = 1;
    grid_barrier<true>(bar, epoch); ++epoch;   // Jt ready (fenced, once)

    // ---- load this block's 8 Jt rows into LDS once, XOR-swizzled ----
    // 16B-granule qi stored at byte (qi*16) ^ (((qi>>3)&7)<<4); bijective.
    for (int idx = t; idx < NPB * (GN / 4); idx += BLK) {   // 4096 float4s
        const int row = idx >> 9;
        const int qi  = idx & 511;
        const float4 v = *(const float4*)&Jt[(size_t)(jb + row) * GN + qi * 4];
        const int byte = (qi * 16) ^ (((qi >> 3) & 7) << 4);
        *(float4*)((char*)&sJ[row][0] + byte) = v;
    }
    __syncthreads();

    // ---- stream decomposition: t = isub*8 + jh*4 + mq ----
    const int mq   = t & 3;          // m-quad: m = mq*4 + mi
    const int jh   = (t >> 2) & 1;   // j-half (4 j's each)
    const int isub = t >> 3;         // 0..63, owns i in [isub*32, isub*32+32)
    const int i0 = isub * 32;
    const int swz = (isub & 7) << 4; // LDS bank swizzle for this thread's stripe
    const char* sJb = (const char*)&sJ[0][0];

    float wj[4];
#pragma unroll
    for (int mi = 0; mi < 4; ++mi) wj[mi] = swJ[mq * 4 + mi];

    for (int s = 0; s < GSTEPS; ++s) {
        const float* __restrict__ aiIn = aiBase + (size_t)s * AISTRIDE;
        float* __restrict__ aiOut = aiBase + (size_t)(s + 1) * AISTRIDE;

        // ---- phase 2: relu-sum stream; J from LDS, ai from global (L3) ----
        float ajv[4][4];
#pragma unroll
        for (int jl = 0; jl < 4; ++jl) {
            const float4 a = *(const float4*)&saj[jh * 4 + jl][mq * 4];
            ajv[jl][0] = a.x; ajv[jl][1] = a.y; ajv[jl][2] = a.z; ajv[jl][3] = a.w;
        }
        const float* __restrict__ Ar[4];
#pragma unroll
        for (int mi = 0; mi < 4; ++mi) Ar[mi] = aiIn + (size_t)(mq * 4 + mi) * GN + i0;

        float acc[4][4];
#pragma unroll
        for (int jl = 0; jl < 4; ++jl)
#pragma unroll
            for (int mi = 0; mi < 4; ++mi) acc[jl][mi] = 0.f;

#pragma unroll 2
        for (int c = 0; c < 8; ++c) {
            float jv[4][4], av[4][4];
            const int jbyte = (i0 * 4 + c * 16) ^ swz;
#pragma unroll
            for (int jl = 0; jl < 4; ++jl) {
                const float4 v = *(const float4*)(sJb + (jh * 4 + jl) * (GN * 4) + jbyte);
                jv[jl][0] = v.x; jv[jl][1] = v.y; jv[jl][2] = v.z; jv[jl][3] = v.w;
            }
#pragma unroll
            for (int mi = 0; mi < 4; ++mi) {
                const float4 v = *(const float4*)(Ar[mi] + c * 4);
                av[mi][0] = v.x; av[mi][1] = v.y; av[mi][2] = v.z; av[mi][3] = v.w;
            }
#pragma unroll
            for (int q = 0; q < 4; ++q)
#pragma unroll
                for (int jl = 0; jl < 4; ++jl)
#pragma unroll
                    for (int mi = 0; mi < 4; ++mi)
                        acc[jl][mi] += fmaxf(fmaf(jv[jl][q], wj[mi],
                                                  av[mi][q] + ajv[jl][mi]), 0.f);
        }

        // reduce over isub-within-wave (lane bits 3..5)
#pragma unroll
        for (int d = 8; d < 64; d <<= 1)
#pragma unroll
            for (int jl = 0; jl < 4; ++jl)
#pragma unroll
                for (int mi = 0; mi < 4; ++mi)
                    acc[jl][mi] += __shfl_xor(acc[jl][mi], d, 64);

        if ((t & 63) < 8) {   // lane = jh*4 + mq
            const int w = t >> 6;
#pragma unroll
            for (int jl = 0; jl < 4; ++jl)
                *(float4*)&spart[w][jh][mq][jl][0] =
                    make_float4(acc[jl][0], acc[jl][1], acc[jl][2], acc[jl][3]);
        }
        __syncthreads();

        // combine 8 wave-partials, update msg (deterministic order)
        if (t < NPB * GMD) {
            const int j = t >> 4, m = t & 15;
            const int jhh = j >> 2, jl = j & 3, mqq = m >> 2, mi = m & 3;
            float ssum = 0.f;
#pragma unroll
            for (int w = 0; w < 8; ++w) ssum += spart[w][jhh][mqq][jl][mi];
            const float mnew = smsg[j][m] + ssum;
            smsg[j][m] = mnew;
            sx[j][GSD + m] = mnew;
        }
        __syncthreads();

        // ---- phase 3: g = W_ih @ x + b_ih ----
        for (int idx = t; idx < NPB * 96; idx += BLK) {
            const int node = idx / 96, r = idx - node * 96;
            float a = sbih[r];
#pragma unroll
            for (int c = 0; c < GSD + GMD; ++c) a = fmaf(sWih[r][c], sx[node][c], a);
            sg[node][r] = a;
        }
        __syncthreads();

        // GRU gates -> h_new
        if (t < NPB * GSD) {
            const int node = t >> 5, k = t & 31;
            const float gr = sg[node][k]           + sbhh[k];
            const float gz = sg[node][GSD + k]     + sbhh[GSD + k];
            const float gn = sg[node][2 * GSD + k];
            const float r_ = 1.f / (1.f + expf(-gr));
            const float z_ = 1.f / (1.f + expf(-gz));
            const float n_ = tanhf(fmaf(r_, sbhh[2 * GSD + k], gn));
            const float hn = (1.f - z_) * n_;
            sh[node][k] = hn;
            sx[node][k] = hn;
        }
        __syncthreads();

        if (s < GSTEPS - 1) {
            // ---- phase 1': ai (write-through, next step's buffer) / aj (LDS) ----
            if (t < 2 * NPB * GMD) {   // 256 threads
                const int which = t >> 7;
                const int node  = (t >> 4) & 7;
                const int m     = t & 15;
                if (which == 0) {
                    float a = fmaf(sb[node], swbi[m], sbm[m]);
#pragma unroll
                    for (int k = 0; k < GSD; ++k) a = fmaf(sWhi[m][k], sh[node][k], a);
                    __hip_atomic_store(&aiOut[(size_t)m * GN + jb + node], a,
                                       __ATOMIC_RELAXED, __HIP_MEMORY_SCOPE_AGENT);
                } else {
                    float a = sb[node] * swbj[m];
#pragma unroll
                    for (int k = 0; k < GSD; ++k) a = fmaf(sWhj[m][k], sh[node][k], a);
                    saj[node][m] = a;
                }
            }
            grid_barrier<false>(bar, epoch); ++epoch;   // fenceless step sync
        }
    }

    // ---- readout logits (write-through) ----
    if (t < NPB) {
        float a = bro[0];
#pragma unroll
        for (int k = 0; k < GSD; ++k) a = fmaf(sh[t][k], swro[k], a);
        __hip_atomic_store(&logits[jb + t], a,
                           __ATOMIC_RELAXED, __HIP_MEMORY_SCOPE_AGENT);
    }
    grid_barrier<false>(bar, epoch); ++epoch;

    // ---- softmax: computed redundantly per block (identical fixed order) ----
    const float4 l4 = *(const float4*)&logits[t * 4];
    float lm = fmaxf(fmaxf(l4.x, l4.y), fmaxf(l4.z, l4.w));
#pragma unroll
    for (int d = 1; d < 64; d <<= 1) lm = fmaxf(lm, __shfl_xor(lm, d, 64));
    if ((t & 63) == 0) sredm[t >> 6] = lm;
    __syncthreads();
    float gmax = sredm[0];
#pragma unroll
    for (int w = 1; w < 8; ++w) gmax = fmaxf(gmax, sredm[w]);
    float es = expf(l4.x - gmax) + expf(l4.y - gmax) +
               expf(l4.z - gmax) + expf(l4.w - gmax);
#pragma unroll
    for (int d = 1; d < 64; d <<= 1) es += __shfl_xor(es, d, 64);
    if ((t & 63) == 0) sreds[t >> 6] = es;
    __syncthreads();
    float tot = 0.f;
#pragma unroll
    for (int w = 0; w < 8; ++w) tot += sreds[w];
    if (t < NPB) out[jb + t] = expf(logits[jb + t] - gmax) / tot;
}

extern "C" void kernel_launch(void* const* d_in, const int* in_sizes, int n_in,
                              void* d_out, int out_size, void* d_ws, size_t ws_size,
                              hipStream_t stream)
{
    const float* J    = (const float*)d_in[0];
    const float* b    = (const float*)d_in[1];
    const float* Wmsg = (const float*)d_in[2];
    const float* bmsg = (const float*)d_in[3];
    const float* Wih  = (const float*)d_in[4];
    // d_in[5] = W_hh: unused by the reference math (only b_hh enters the gates)
    const float* bih  = (const float*)d_in[6];
    const float* bhh  = (const float*)d_in[7];
    const float* Wro  = (const float*)d_in[8];
    const float* bro  = (const float*)d_in[9];
    float* out = (float*)d_out;

    // workspace layout (floats): Jt 16.8MB + 10 aiT buffers (1.32MB) + misc
    float* ws     = (float*)d_ws;
    float* Jt     = ws;                                   // N*N
    float* aiBase = Jt + (size_t)GN * GN;                 // GSTEPS * AISTRIDE
    float* logits = aiBase + (size_t)GSTEPS * AISTRIDE;   // N
    int*   bar    = (int*)(logits + GN);                  // barrier counters

    hipMemsetAsync(bar, 0, 1024, stream);
    ggnn_persistent<<<NBLK, BLK, 0, stream>>>(J, b, Wmsg, bmsg, Wih, bih, bhh,
                                              Wro, bro, Jt, aiBase, logits,
                                              bar, out);
}